// Round 2
// baseline (784.830 us; speedup 1.0000x reference)
//
#include <hip/hip_runtime.h>
#include <hip/hip_bf16.h>

typedef __attribute__((ext_vector_type(4))) float f32x4;
typedef __attribute__((ext_vector_type(8))) short bf16x8;
typedef __attribute__((ext_vector_type(4))) short bf16x4;

#define S_LEN 2048
#define D_DIM 128
#define QBLK 64
#define KVBLK 64
#define NKV (S_LEN / KVBLK)

__device__ __forceinline__ unsigned short f2bf(float f) {
    union { float f; unsigned u; } v; v.f = f;
    unsigned r = v.u + 0x7FFFu + ((v.u >> 16) & 1u);  // RNE
    return (unsigned short)(r >> 16);
}
__device__ __forceinline__ float bf2f(unsigned short h) {
    union { unsigned u; float f; } v; v.u = ((unsigned)h) << 16;
    return v.f;
}

// softmax(x2 @ x3^T) @ x3 ; Q = x2, K = V = x3, no scale.
// QK^T in split-bf16 (hi+lo) for fp32-grade scores; PV in plain bf16.
__global__ __launch_bounds__(256, 1) void attn_kernel(
    const float* __restrict__ Q, const float* __restrict__ KV,
    float* __restrict__ Out)
{
    // XCD-aware swizzle: 2048 blocks % 8 == 0 -> bijective chunked map.
    unsigned b = blockIdx.x;
    unsigned cpx = gridDim.x >> 3;
    unsigned work = (b & 7u) * cpx + (b >> 3);
    unsigned head = work >> 5;   // 64 heads
    unsigned qt = work & 31u;    // 32 q-tiles per head

    const float* Qh = Q + (size_t)head * (S_LEN * D_DIM) + (size_t)qt * QBLK * D_DIM;
    const float* Kh = KV + (size_t)head * (S_LEN * D_DIM);
    float* Oh = Out + (size_t)head * (S_LEN * D_DIM) + (size_t)qt * QBLK * D_DIM;

    const int tid = threadIdx.x;
    const int wv = tid >> 6;
    const int lane = tid & 63;
    const int lo = lane & 15;
    const int hi = lane >> 4;

    __shared__ __align__(16) short KshH[KVBLK * D_DIM];     // K hi, [kv][d], swizzled
    __shared__ __align__(16) short KshL[KVBLK * D_DIM];     // K lo, [kv][d], swizzled
    __shared__ __align__(16) short Vsh[D_DIM * KVBLK];      // [d][kv] (transposed), swizzled
    __shared__ __align__(16) short Psh[4][16 * KVBLK];      // per-wave [q][kv], swizzled

    // ---- Q fragments (hi+lo) for this wave: Q[wv*16+lo][kc*32 + hi*8 + j] ----
    bf16x8 qh[4], ql[4];
    {
        const float* qr = Qh + (wv * 16 + lo) * D_DIM + hi * 8;
        #pragma unroll
        for (int kc = 0; kc < 4; ++kc) {
            f32x4 a = *(const f32x4*)(qr + kc * 32);
            f32x4 c = *(const f32x4*)(qr + kc * 32 + 4);
            float v[8] = {a[0], a[1], a[2], a[3], c[0], c[1], c[2], c[3]};
            #pragma unroll
            for (int j = 0; j < 8; ++j) {
                unsigned short hb = f2bf(v[j]);
                qh[kc][j] = (short)hb;
                ql[kc][j] = (short)f2bf(v[j] - bf2f(hb));
            }
        }
    }

    f32x4 oacc[8];
    #pragma unroll
    for (int n = 0; n < 8; ++n) oacc[n] = (f32x4){0.f, 0.f, 0.f, 0.f};
    float m_run = -1e30f, l_run = 0.f;

    for (int kt = 0; kt < NKV; ++kt) {
        const float* kbase = Kh + (size_t)kt * KVBLK * D_DIM;

        // ---- stage K tile [64][128] fp32 -> bf16 hi+lo LDS (coalesced) ----
        #pragma unroll
        for (int j = 0; j < 8; ++j) {
            int flat = tid + j * 256;        // float4 id, 2048 per tile
            int row = flat >> 5;             // 32 float4 per row
            int c4 = flat & 31;
            f32x4 a = *(const f32x4*)(kbase + row * D_DIM + c4 * 4);
            bf16x4 wH, wL;
            #pragma unroll
            for (int e = 0; e < 4; ++e) {
                unsigned short hb = f2bf(a[e]);
                wH[e] = (short)hb;
                wL[e] = (short)f2bf(a[e] - bf2f(hb));
            }
            int col = (c4 * 4) ^ ((row & 7) << 3);
            *(bf16x4*)&KshH[row * D_DIM + col] = wH;
            *(bf16x4*)&KshL[row * D_DIM + col] = wL;
        }
        // ---- stage V transposed: Vsh[d][kv] = V[kv][d] (plain bf16) ----
        {
            int d0 = (tid & 15) * 8;
            int kv0 = (tid >> 4) * 4;
            f32x4 va[4][2];
            #pragma unroll
            for (int i = 0; i < 4; ++i) {
                va[i][0] = *(const f32x4*)(kbase + (kv0 + i) * D_DIM + d0);
                va[i][1] = *(const f32x4*)(kbase + (kv0 + i) * D_DIM + d0 + 4);
            }
            #pragma unroll
            for (int jd = 0; jd < 8; ++jd) {
                bf16x4 w;
                #pragma unroll
                for (int i = 0; i < 4; ++i)
                    w[i] = (short)f2bf(va[i][jd >> 2][jd & 3]);
                int kcol = kv0 ^ (jd << 3);   // (d0+jd)&7 == jd
                *(bf16x4*)&Vsh[(d0 + jd) * KVBLK + kcol] = w;
            }
        }
        __syncthreads();

        // ---- swapped QK^T: S^T = K_tile @ Q_wave^T, 3-term split-bf16 ----
        f32x4 st[4];
        #pragma unroll
        for (int m = 0; m < 4; ++m) st[m] = (f32x4){0.f, 0.f, 0.f, 0.f};
        #pragma unroll
        for (int m = 0; m < 4; ++m) {
            int row = m * 16 + lo;
            int sw = (row & 7) << 3;
            #pragma unroll
            for (int kc = 0; kc < 4; ++kc) {
                int off = row * D_DIM + ((kc * 32 + hi * 8) ^ sw);
                bf16x8 kh = *(const bf16x8*)&KshH[off];
                bf16x8 kl = *(const bf16x8*)&KshL[off];
                st[m] = __builtin_amdgcn_mfma_f32_16x16x32_bf16(kh, qh[kc], st[m], 0, 0, 0);
                st[m] = __builtin_amdgcn_mfma_f32_16x16x32_bf16(kh, ql[kc], st[m], 0, 0, 0);
                st[m] = __builtin_amdgcn_mfma_f32_16x16x32_bf16(kl, qh[kc], st[m], 0, 0, 0);
            }
        }
        // lane holds S^T[kv = m*16 + hi*4 + r][q = wv*16 + lo]

        // ---- online softmax (reduce over kv: in-lane + xor16 + xor32) ----
        float tmax = -1e30f;
        #pragma unroll
        for (int m = 0; m < 4; ++m)
            #pragma unroll
            for (int r = 0; r < 4; ++r) tmax = fmaxf(tmax, st[m][r]);
        tmax = fmaxf(tmax, __shfl_xor(tmax, 16, 64));
        tmax = fmaxf(tmax, __shfl_xor(tmax, 32, 64));
        float mnew = fmaxf(m_run, tmax);
        float scale = __expf(m_run - mnew);
        float ls = 0.f;
        #pragma unroll
        for (int m = 0; m < 4; ++m) {
            #pragma unroll
            for (int r = 0; r < 4; ++r) {
                float p = __expf(st[m][r] - mnew);
                st[m][r] = p;
                ls += p;
            }
        }
        ls += __shfl_xor(ls, 16, 64);
        ls += __shfl_xor(ls, 32, 64);
        l_run = l_run * scale + ls;
        m_run = mnew;

        // ---- P -> LDS (bf16), row q=lo, 4 consecutive kv per chunk ----
        const int swp = (lo & 7) << 3;
        #pragma unroll
        for (int m = 0; m < 4; ++m) {
            bf16x4 w;
            #pragma unroll
            for (int r = 0; r < 4; ++r) w[r] = (short)f2bf(st[m][r]);
            int col = (m * 16 + hi * 4) ^ swp;
            *(bf16x4*)&Psh[wv][lo * KVBLK + col] = w;
        }

        // ---- rescale O by exp(m_old - m_new), per out-row q = hi*4 + r ----
        float sc[4];
        #pragma unroll
        for (int r = 0; r < 4; ++r) sc[r] = __shfl(scale, hi * 4 + r, 64);
        #pragma unroll
        for (int n = 0; n < 8; ++n)
            #pragma unroll
            for (int r = 0; r < 4; ++r) oacc[n][r] *= sc[r];

        // ---- PV: O += P @ V ----
        #pragma unroll
        for (int kc2 = 0; kc2 < 2; ++kc2) {
            bf16x8 pf = *(const bf16x8*)&Psh[wv][lo * KVBLK + ((kc2 * 32 + hi * 8) ^ swp)];
            #pragma unroll
            for (int n = 0; n < 8; ++n) {
                int d = n * 16 + lo;
                bf16x8 vf = *(const bf16x8*)&Vsh[d * KVBLK + ((kc2 * 32 + hi * 8) ^ ((d & 7) << 3))];
                oacc[n] = __builtin_amdgcn_mfma_f32_16x16x32_bf16(pf, vf, oacc[n], 0, 0, 0);
            }
        }
        __syncthreads();
    }

    // ---- epilogue: O / l, write fp32 ----
    float inv = 1.0f / l_run;   // valid at lane's q = lo
    float rl[4];
    #pragma unroll
    for (int r = 0; r < 4; ++r) rl[r] = __shfl(inv, hi * 4 + r, 64);
    #pragma unroll
    for (int n = 0; n < 8; ++n)
        #pragma unroll
        for (int r = 0; r < 4; ++r)
            Oh[(wv * 16 + hi * 4 + r) * D_DIM + n * 16 + lo] = oacc[n][r] * rl[r];
}

extern "C" void kernel_launch(void* const* d_in, const int* in_sizes, int n_in,
                              void* d_out, int out_size, void* d_ws, size_t ws_size,
                              hipStream_t stream) {
    const float* x2 = (const float*)d_in[0];
    const float* x3 = (const float*)d_in[1];
    float* out = (float*)d_out;
    dim3 grid(2048), block(256);
    hipLaunchKernelGGL(attn_kernel, grid, block, 0, stream, x2, x3, out);
}